// Round 16
// baseline (152.104 us; speedup 1.0000x reference)
//
#include <hip/hip_runtime.h>
#include <hip/hip_bf16.h>

#define B_ 4
#define T_ 2048
#define D_ 2048
#define DV_ 1024
#define TIMG_ 8
#define NLAT_ 64
#define H_ 16
#define DH_ 64
#define INNER_ 1024
#define J_ (TIMG_ * NLAT_)  // 512

using f32x4 = __attribute__((ext_vector_type(4))) float;
using bf16x8 = __attribute__((ext_vector_type(8))) short;
using bf16x4 = __attribute__((ext_vector_type(4))) short;

__device__ __forceinline__ unsigned short f2bf(float f) {
  union { float f; unsigned int u; } c{f};
  unsigned int r = c.u + 0x7FFFu + ((c.u >> 16) & 1u);  // RNE
  return (unsigned short)(r >> 16);
}

__device__ __forceinline__ void stage16(const unsigned short* g, unsigned short* l) {
  __builtin_amdgcn_global_load_lds(
      (const __attribute__((address_space(1))) unsigned int*)g,
      (__attribute__((address_space(3))) unsigned int*)l, 16, 0, 0);
}

// ========== prep v4: uv-partial(16) | scan(4) | Wq(512) | Wkv/Wout(1024) | media(1024) ==========
__global__ __launch_bounds__(256) void prep_kernel(
    const void* __restrict__ locs,
    const float* __restrict__ g, const float* __restrict__ bta,
    const float* __restrict__ Wq, const float* __restrict__ Wkv,
    const float* __restrict__ Wout, const float* __restrict__ media,
    int* __restrict__ img_idx,
    unsigned short* __restrict__ wqt, unsigned short* __restrict__ wkvt,
    unsigned short* __restrict__ woutt, unsigned short* __restrict__ medb,
    float* __restrict__ uvp, float* __restrict__ vvp) {
  __shared__ __align__(16) float smf[64 * 68];
  const int tid = threadIdx.x;
  int blk = blockIdx.x;

  if (blk < 16) {
    const int c4 = tid * 4;
    const float* wbase = Wq + (size_t)blk * 128 * INNER_ + c4;
    f32x4 u4 = {0.f, 0.f, 0.f, 0.f}, v4 = {0.f, 0.f, 0.f, 0.f};
    for (int k = 0; k < 128; ++k) {
      f32x4 w = *(const f32x4*)(wbase + (size_t)k * INNER_);
      const float gk = g[blk * 128 + k];
      const float bk = bta[blk * 128 + k];
      u4 += gk * w;
      v4 += bk * w;
    }
    *(f32x4*)(uvp + blk * INNER_ + c4) = u4 * 0.125f;
    *(f32x4*)(vvp + blk * INNER_ + c4) = v4 * 0.125f;
    return;
  }
  blk -= 16;
  if (blk < 4) {
    int* sm = (int*)smf;
    const int b = blk;
    const unsigned char* u8 = (const unsigned char*)locs;
    int cnt = 0;
    for (int i = tid; i < B_ * T_; i += 256) cnt += (u8[i] != 0) ? 1 : 0;
    sm[tid] = cnt;
    __syncthreads();
    for (int off = 128; off > 0; off >>= 1) {
      if (tid < off) sm[tid] += sm[tid + off];
      __syncthreads();
    }
    const bool u8mode = (sm[0] == B_ * TIMG_);
    __syncthreads();
    const int base = b * T_ + tid * 8;
    const int* i32 = (const int*)locs;
    int v[8];
    int ts = 0;
#pragma unroll
    for (int j = 0; j < 8; ++j) {
      v[j] = u8mode ? (u8[base + j] != 0 ? 1 : 0) : (i32[base + j] != 0 ? 1 : 0);
      ts += v[j];
    }
    sm[tid] = ts;
    __syncthreads();
    for (int off = 1; off < 256; off <<= 1) {
      int add = (tid >= off) ? sm[tid - off] : 0;
      __syncthreads();
      sm[tid] += add;
      __syncthreads();
    }
    int acc = sm[tid] - ts;
#pragma unroll
    for (int j = 0; j < 8; ++j) {
      acc += v[j];
      img_idx[base + j] = acc - 1;
    }
    return;
  }
  blk -= 4;
  if (blk < 512) {
    const int by = blk >> 4, bx = blk & 15;
    const int br = by * 64, bc = bx * 64;
    float (*tile)[68] = (float(*)[68])smf;
    const int r = tid >> 4;
    const int c4 = (tid & 15) * 4;
#pragma unroll
    for (int rr = 0; rr < 4; ++rr)
      *(float4*)&tile[r + rr * 16][c4] =
          *(const float4*)&Wq[(size_t)(br + r + rr * 16) * INNER_ + bc + c4];
    __syncthreads();
    const int oc = tid >> 2;
    const int rb = (tid & 3) * 16;
    bf16x8 o0, o1;
#pragma unroll
    for (int e = 0; e < 8; ++e) {
      o0[e] = (short)f2bf(tile[rb + e][oc] * g[br + rb + e] * 0.125f);
      o1[e] = (short)f2bf(tile[rb + 8 + e][oc] * g[br + rb + 8 + e] * 0.125f);
    }
    unsigned short* op = wqt + (size_t)(bc + oc) * D_ + br + rb;
    *(bf16x8*)op = o0;
    *(bf16x8*)(op + 8) = o1;
    return;
  }
  blk -= 512;
  if (blk < 1024) {
    const float* tin = (blk < 512) ? Wkv : Wout;
    unsigned short* tout = (blk < 512) ? wkvt : woutt;
    int idx = blk & 511;
    const int by = idx >> 5, bx = idx & 31;
    const int br = by * 64, bc = bx * 64;
    float (*tile)[68] = (float(*)[68])smf;
    const int r = tid >> 4;
    const int c4 = (tid & 15) * 4;
#pragma unroll
    for (int rr = 0; rr < 4; ++rr)
      *(float4*)&tile[r + rr * 16][c4] =
          *(const float4*)&tin[(size_t)(br + r + rr * 16) * (2 * INNER_) + bc + c4];
    __syncthreads();
    const int oc = tid >> 2;
    const int rb = (tid & 3) * 16;
    bf16x8 o0, o1;
#pragma unroll
    for (int e = 0; e < 8; ++e) {
      o0[e] = (short)f2bf(tile[rb + e][oc]);
      o1[e] = (short)f2bf(tile[rb + 8 + e][oc]);
    }
    unsigned short* op = tout + (size_t)(bc + oc) * DV_ + br + rb;
    *(bf16x8*)op = o0;
    *(bf16x8*)(op + 8) = o1;
    return;
  }
  blk -= 1024;
  const int i = blk * 512 + tid * 2;
  float4 a = ((const float4*)media)[i];
  float4 b2 = ((const float4*)media)[i + 1];
  ((ushort4*)medb)[i] = make_ushort4(f2bf(a.x), f2bf(a.y), f2bf(a.z), f2bf(a.w));
  ((ushort4*)medb)[i + 1] = make_ushort4(f2bf(b2.x), f2bf(b2.y), f2bf(b2.z), f2bf(b2.w));
}

// ========== gemm1 body (R14 v4): 2-phase, reg-staged A + LN epilogue, XCD-grouped map ==========
__device__ __forceinline__ void gemm1_body(
    int bid, unsigned short* lds,
    const float* __restrict__ Xg, const unsigned short* __restrict__ Bg,
    unsigned short* __restrict__ Cv,
    const float* __restrict__ uvp, const float* __restrict__ vvp) {
  const int N = INNER_, K = D_;
  const int tid = threadIdx.x;
  const int lane = tid & 63;
  const int wave = tid >> 6;
  const int l15 = lane & 15;
  const int lg8 = (lane >> 4) << 3;
  const int wr64 = (wave >> 2) << 6;
  const int wc16 = (wave & 3) << 4;

  const int xcd = bid & 7;
  const int i5 = bid >> 3;
  const long row0 = (long)(xcd * 8 + (i5 >> 2)) << 7;
  const long col0 = (long)(i5 & 3) << 8;

  const int ar = tid >> 2;
  const int aq = tid & 3;
  const float4* xrow = (const float4*)(Xg + (size_t)(row0 + ar) * K) + aq * 4;

  auto stB = [&](int t, int r) {
    const int i = r * 512 + tid;
    const int row = i >> 3;
    const int c = (i & 7) ^ (row & 7);
    stage16(Bg + (size_t)(col0 + row) * K + (t << 6) + c * 8,
            &lds[16384 + (t % 3) * 16384 + i * 8]);
  };

  float s_part = 0.f, sq_part = 0.f;
  float4 a0, a1, a2, a3;
  auto aload = [&](int t) {
    const float4* p = xrow + t * 16;
    a0 = p[0]; a1 = p[1]; a2 = p[2]; a3 = p[3];
  };
  auto acvt = [&](int t) {
    unsigned short* Ab = &lds[(t & 1) * 8192];
    float v0[8] = {a0.x, a0.y, a0.z, a0.w, a1.x, a1.y, a1.z, a1.w};
    float v1[8] = {a2.x, a2.y, a2.z, a2.w, a3.x, a3.y, a3.z, a3.w};
    bf16x8 w0, w1;
#pragma unroll
    for (int e = 0; e < 8; ++e) {
      s_part += v0[e] + v1[e];
      sq_part += v0[e] * v0[e] + v1[e] * v1[e];
      w0[e] = (short)f2bf(v0[e]);
      w1[e] = (short)f2bf(v1[e]);
    }
    *(bf16x8*)(Ab + ar * 64 + (((aq * 2) ^ (ar & 7)) << 3)) = w0;
    *(bf16x8*)(Ab + ar * 64 + (((aq * 2 + 1) ^ (ar & 7)) << 3)) = w1;
  };

  const int NT = K >> 6;  // 32
  aload(0); acvt(0);
  aload(1);
  stB(0, 0); stB(0, 1); stB(0, 2); stB(0, 3);
  stB(1, 0); stB(1, 1); stB(1, 2); stB(1, 3);
  asm volatile("s_waitcnt vmcnt(4)" ::: "memory");
  asm volatile("s_waitcnt lgkmcnt(0)" ::: "memory");
  asm volatile("s_barrier" ::: "memory");

  f32x4 acc[4][4] = {};
  for (int t = 0; t < NT; ++t) {
    const unsigned short* Ab = &lds[(t & 1) * 8192];
    const unsigned short* Bb = &lds[16384 + (t % 3) * 16384];
    bf16x8 af[4][2], bfr[4][2];
    // ---------- P1 ----------
#pragma unroll
    for (int m = 0; m < 4; ++m)
#pragma unroll
      for (int kk = 0; kk < 2; ++kk) {
        const int row = wr64 + m * 16 + l15;
        af[m][kk] = *(const bf16x8*)(Ab + row * 64 + ((kk * 32 + lg8) ^ ((row & 7) << 3)));
      }
#pragma unroll
    for (int n = 0; n < 2; ++n)
#pragma unroll
      for (int kk = 0; kk < 2; ++kk) {
        const int brow = n * 64 + wc16 + l15;
        bfr[n][kk] = *(const bf16x8*)(Bb + brow * 64 + ((kk * 32 + lg8) ^ ((brow & 7) << 3)));
      }
    if (t + 1 < NT) {
      acvt(t + 1);
      if (t + 2 < NT) aload(t + 2);
    }
    asm volatile("s_barrier" ::: "memory");
    asm volatile("s_waitcnt lgkmcnt(0)" ::: "memory");
    __builtin_amdgcn_s_setprio(1);
#pragma unroll
    for (int m = 0; m < 4; ++m)
#pragma unroll
      for (int n = 0; n < 2; ++n)
#pragma unroll
        for (int kk = 0; kk < 2; ++kk)
          acc[m][n] = __builtin_amdgcn_mfma_f32_16x16x32_bf16(af[m][kk], bfr[n][kk], acc[m][n], 0, 0, 0);
    __builtin_amdgcn_s_setprio(0);
    asm volatile("s_barrier" ::: "memory");
    // ---------- P2 ----------
#pragma unroll
    for (int n = 2; n < 4; ++n)
#pragma unroll
      for (int kk = 0; kk < 2; ++kk) {
        const int brow = n * 64 + wc16 + l15;
        bfr[n][kk] = *(const bf16x8*)(Bb + brow * 64 + ((kk * 32 + lg8) ^ ((brow & 7) << 3)));
      }
    if (t + 2 < NT) {
      stB(t + 2, 0); stB(t + 2, 1); stB(t + 2, 2); stB(t + 2, 3);
      asm volatile("s_waitcnt vmcnt(8)" ::: "memory");
    } else {
      asm volatile("s_waitcnt vmcnt(0)" ::: "memory");
    }
    asm volatile("s_barrier" ::: "memory");
    asm volatile("s_waitcnt lgkmcnt(0)" ::: "memory");
    __builtin_amdgcn_s_setprio(1);
#pragma unroll
    for (int m = 0; m < 4; ++m)
#pragma unroll
      for (int n = 2; n < 4; ++n)
#pragma unroll
        for (int kk = 0; kk < 2; ++kk)
          acc[m][n] = __builtin_amdgcn_mfma_f32_16x16x32_bf16(af[m][kk], bfr[n][kk], acc[m][n], 0, 0, 0);
    __builtin_amdgcn_s_setprio(0);
    asm volatile("s_barrier" ::: "memory");
  }

  // ---- stats reduce in A-region ----
  float* sred = (float*)lds;
  sred[tid] = s_part;
  sred[512 + tid] = sq_part;
  __syncthreads();
  if (tid < 128) {
    float s = sred[tid * 4] + sred[tid * 4 + 1] + sred[tid * 4 + 2] + sred[tid * 4 + 3];
    float sq = sred[512 + tid * 4] + sred[512 + tid * 4 + 1] + sred[512 + tid * 4 + 2] + sred[512 + tid * 4 + 3];
    float mu = s * (1.0f / D_);
    sred[1024 + tid] = mu;
    sred[1152 + tid] = rsqrtf(sq * (1.0f / D_) - mu * mu + 1e-5f);
  }
  __syncthreads();

  const int cr = (lane >> 4) << 2;
#pragma unroll
  for (int n = 0; n < 4; ++n) {
    const long col = col0 + n * 64 + wc16 + l15;
    float uu = 0.f, vv = 0.f;
#pragma unroll
    for (int i = 0; i < 16; ++i) {
      uu += uvp[i * INNER_ + col];
      vv += vvp[i * INNER_ + col];
    }
#pragma unroll
    for (int m = 0; m < 4; ++m)
#pragma unroll
      for (int j = 0; j < 4; ++j) {
        const int lr = wr64 + m * 16 + cr + j;
        const float mu = sred[1024 + lr];
        const float rstd = sred[1152 + lr];
        Cv[(row0 + lr) * (size_t)N + col] = f2bf(rstd * (acc[m][n][j] - mu * uu) + vv);
      }
  }
}

// ========== gemm2 body: 128x256 2-phase, M=2048/N=2048/K=1024, V-cols transposed to vt ==========
__device__ __forceinline__ void gemm2_body(
    int bid, unsigned short* lds,
    const unsigned short* __restrict__ Ag, const unsigned short* __restrict__ Bg,
    unsigned short* __restrict__ Cv, unsigned short* __restrict__ vtp) {
  const int M = B_ * J_, N = 2 * INNER_, K = DV_;
  const int tid = threadIdx.x;
  const int lane = tid & 63;
  const int wave = tid >> 6;
  const int l15 = lane & 15;
  const int lg8 = (lane >> 4) << 3;
  const int wr64 = (wave >> 2) << 6;
  const int wc16 = (wave & 3) << 4;

  // bijective XCD swizzle for sub-grid of 128
  const int wg = (bid & 7) * 16 + (bid >> 3);
  const int gridM = M >> 7;  // 16
  const long row0 = (long)(wg % gridM) << 7;
  const long col0 = (long)(wg / gridM) << 8;

  auto stA = [&](int t, int r) {
    const int i = r * 512 + tid;
    const int row = i >> 3;
    const int c = (i & 7) ^ (row & 7);
    stage16(Ag + (size_t)(row0 + row) * K + (t << 6) + c * 8,
            &lds[(t & 1) * 8192 + i * 8]);
  };
  auto stB = [&](int t, int r) {
    const int i = r * 512 + tid;
    const int row = i >> 3;
    const int c = (i & 7) ^ (row & 7);
    stage16(Bg + (size_t)(col0 + row) * K + (t << 6) + c * 8,
            &lds[16384 + (t % 3) * 16384 + i * 8]);
  };

  const int NT = K >> 6;  // 16
  stB(0, 0); stB(0, 1); stB(0, 2); stB(0, 3);
  stA(0, 0); stA(0, 1);
  stB(1, 0); stB(1, 1); stB(1, 2); stB(1, 3);
  asm volatile("s_waitcnt vmcnt(4)" ::: "memory");
  asm volatile("s_barrier" ::: "memory");

  f32x4 acc[4][4] = {};
  for (int t = 0; t < NT; ++t) {
    const unsigned short* Ab = &lds[(t & 1) * 8192];
    const unsigned short* Bb = &lds[16384 + (t % 3) * 16384];
    bf16x8 af[4][2], bfr[4][2];
#pragma unroll
    for (int m = 0; m < 4; ++m)
#pragma unroll
      for (int kk = 0; kk < 2; ++kk) {
        const int row = wr64 + m * 16 + l15;
        af[m][kk] = *(const bf16x8*)(Ab + row * 64 + ((kk * 32 + lg8) ^ ((row & 7) << 3)));
      }
#pragma unroll
    for (int n = 0; n < 2; ++n)
#pragma unroll
      for (int kk = 0; kk < 2; ++kk) {
        const int brow = n * 64 + wc16 + l15;
        bfr[n][kk] = *(const bf16x8*)(Bb + brow * 64 + ((kk * 32 + lg8) ^ ((brow & 7) << 3)));
      }
    if (t + 1 < NT) { stA(t + 1, 0); stA(t + 1, 1); }
    if (t + 2 < NT) { stB(t + 2, 0); stB(t + 2, 1); }
    asm volatile("s_barrier" ::: "memory");
    asm volatile("s_waitcnt lgkmcnt(0)" ::: "memory");
    __builtin_amdgcn_s_setprio(1);
#pragma unroll
    for (int m = 0; m < 4; ++m)
#pragma unroll
      for (int n = 0; n < 2; ++n)
#pragma unroll
        for (int kk = 0; kk < 2; ++kk)
          acc[m][n] = __builtin_amdgcn_mfma_f32_16x16x32_bf16(af[m][kk], bfr[n][kk], acc[m][n], 0, 0, 0);
    __builtin_amdgcn_s_setprio(0);
    asm volatile("s_barrier" ::: "memory");
#pragma unroll
    for (int n = 2; n < 4; ++n)
#pragma unroll
      for (int kk = 0; kk < 2; ++kk) {
        const int brow = n * 64 + wc16 + l15;
        bfr[n][kk] = *(const bf16x8*)(Bb + brow * 64 + ((kk * 32 + lg8) ^ ((brow & 7) << 3)));
      }
    if (t + 2 < NT) {
      stB(t + 2, 2); stB(t + 2, 3);
      asm volatile("s_waitcnt vmcnt(4)" ::: "memory");
    } else {
      asm volatile("s_waitcnt vmcnt(0)" ::: "memory");
    }
    asm volatile("s_barrier" ::: "memory");
    asm volatile("s_waitcnt lgkmcnt(0)" ::: "memory");
    __builtin_amdgcn_s_setprio(1);
#pragma unroll
    for (int m = 0; m < 4; ++m)
#pragma unroll
      for (int n = 2; n < 4; ++n)
#pragma unroll
        for (int kk = 0; kk < 2; ++kk)
          acc[m][n] = __builtin_amdgcn_mfma_f32_16x16x32_bf16(af[m][kk], bfr[n][kk], acc[m][n], 0, 0, 0);
    __builtin_amdgcn_s_setprio(0);
    asm volatile("s_barrier" ::: "memory");
  }

  const int cr = (lane >> 4) << 2;

  if (col0 >= INNER_) {
    // ---- transposed epilogue: acc -> LDS [d_local][key_local] (pad 136) -> vt ----
    __syncthreads();
    unsigned short* tp = lds;
#pragma unroll
    for (int m = 0; m < 4; ++m)
#pragma unroll
      for (int n = 0; n < 4; ++n)
#pragma unroll
        for (int j = 0; j < 4; ++j)
          tp[(n * 64 + wc16 + l15) * 136 + (wr64 + m * 16 + cr + j)] = f2bf(acc[m][n][j]);
    __syncthreads();
    const int dloc = tid >> 1;
    const int kh = (tid & 1) * 64;
    const int b = (int)(row0 >> 9);
    const int j0 = (int)(row0 & 511);
    unsigned short* dst = vtp + ((size_t)b * INNER_ + (col0 - INNER_) + dloc) * J_ + j0 + kh;
    const unsigned short* src = tp + dloc * 136 + kh;
#pragma unroll
    for (int e = 0; e < 8; ++e)
      *(bf16x8*)(dst + e * 8) = *(const bf16x8*)(src + e * 8);
    return;
  }

#pragma unroll
  for (int m = 0; m < 4; ++m)
#pragma unroll
    for (int n = 0; n < 4; ++n)
#pragma unroll
      for (int j = 0; j < 4; ++j) {
        const size_t idx = (row0 + wr64 + m * 16 + cr + j) * (size_t)N + col0 + n * 64 + wc16 + l15;
        Cv[idx] = f2bf(acc[m][n][j]);
      }
}

// ========== merged dispatch: bids 0-127 -> GEMM2, 128-383 -> GEMM1 (independent) ==========
__global__ __launch_bounds__(512, 2) void g12_kernel(
    const float* __restrict__ x, const unsigned short* __restrict__ wqt,
    unsigned short* __restrict__ qb,
    const float* __restrict__ uvp, const float* __restrict__ vvp,
    const unsigned short* __restrict__ medb, const unsigned short* __restrict__ wkvt,
    unsigned short* __restrict__ kvb, unsigned short* __restrict__ vt) {
  __shared__ __align__(16) unsigned short lds[65536];
  const int bid = (int)blockIdx.x;
  if (bid < 128)
    gemm2_body(bid, lds, medb, wkvt, kvb, vt);
  else
    gemm1_body(bid - 128, lds, x, wqt, qb, uvp, vvp);
}

// ============ 256x256 deep-pipelined MFMA GEMM (4-phase, BK=64) ============
template <bool BF16OUT>
__global__ __launch_bounds__(512, 2) void gemm256(const unsigned short* __restrict__ Ag,
                                                  const unsigned short* __restrict__ Bg,
                                                  void* __restrict__ Cv,
                                                  int M, int N, int K) {
  __shared__ __align__(16) unsigned short lds[2][32768];
  const int tid = threadIdx.x;
  const int lane = tid & 63;
  const int wave = tid >> 6;
  const int l15 = lane & 15;
  const int lg8 = (lane >> 4) << 3;
  const int wm = (wave >> 2) << 7;
  const int wn = (wave & 3) << 6;

  const int nwg = gridDim.x;
  int wg = ((int)blockIdx.x & 7) * (nwg >> 3) + ((int)blockIdx.x >> 3);
  const int gridM = M >> 8;
  const long row0 = (long)(wg % gridM) << 8;
  const long col0 = (long)(wg / gridM) << 8;

  auto stA = [&](int buf, int kt, int r) {
    const int i = r * 512 + tid;
    const int row = i >> 3;
    const int c = (i & 7) ^ (row & 7);
    stage16(Ag + (size_t)(row0 + row) * K + kt + c * 8, &lds[buf][i * 8]);
  };
  auto stB = [&](int buf, int kt, int r) {
    const int i = r * 512 + tid;
    const int row = i >> 3;
    const int c = (i & 7) ^ (row & 7);
    stage16(Bg + (size_t)(col0 + row) * K + kt + c * 8, &lds[buf][16384 + i * 8]);
  };

  const int NT = K >> 6;
  stB(0, 0, 0); stB(0, 0, 1); stB(0, 0, 2); stB(0, 0, 3);
  stA(0, 0, 0); stA(0, 0, 1); stA(0, 0, 2); stA(0, 0, 3);
  stB(1, 64, 0); stB(1, 64, 1); stB(1, 64, 2); stB(1, 64, 3);
  asm volatile("s_waitcnt vmcnt(4)" ::: "memory");
  asm volatile("s_barrier" ::: "memory");

  f32x4 acc[8][4] = {};
  int cur = 0;
  for (int t = 0; t < NT; ++t, cur ^= 1) {
    const unsigned short* Ab = &lds[cur][0];
    const unsigned short* Bb = &lds[cur][16384];
    bf16x8 af[4][2], bfr[4][2];
    const int ktn = (t + 1) << 6;
    const int ktn2 = (t + 2) << 6;
#pragma unroll
    for (int m = 0; m < 4; ++m)
#pragma unroll
      for (int kk = 0; kk < 2; ++kk) {
        const int row = wm + m * 16 + l15;
        af[m][kk] = *(const bf16x8*)(Ab + row * 64 + ((kk * 32 + lg8) ^ ((row & 7) << 3)));
      }
#pragma unroll
    for (int n = 0; n < 2; ++n)
#pragma unroll
      for (int kk = 0; kk < 2; ++kk) {
        const int brow = wn + n * 16 + l15;
        bfr[n][kk] = *(const bf16x8*)(Bb + brow * 64 + ((kk * 32 + lg8) ^ ((brow & 7) << 3)));
      }
    if (t + 1 < NT) { stA(cur ^ 1, ktn, 0); stA(cur ^ 1, ktn, 1); }
    asm volatile("s_barrier" ::: "memory");
    asm volatile("s_waitcnt lgkmcnt(0)" ::: "memory");
    __builtin_amdgcn_s_setprio(1);
#pragma unroll
    for (int m = 0; m < 4; ++m)
#pragma unroll
      for (int n = 0; n < 2; ++n)
#pragma unroll
        for (int kk = 0; kk < 2; ++kk)
          acc[m][n] = __builtin_amdgcn_mfma_f32_16x16x32_bf16(af[m][kk], bfr[n][kk], acc[m][n], 0, 0, 0);
    __builtin_amdgcn_s_setprio(0);
    asm volatile("s_barrier" ::: "memory");
#pragma unroll
    for (int n = 2; n < 4; ++n)
#pragma unroll
      for (int kk = 0; kk < 2; ++kk) {
        const int brow = wn + n * 16 + l15;
        bfr[n][kk] = *(const bf16x8*)(Bb + brow * 64 + ((kk * 32 + lg8) ^ ((brow & 7) << 3)));
      }
    if (t + 1 < NT) { stA(cur ^ 1, ktn, 2); stA(cur ^ 1, ktn, 3); }
    asm volatile("s_barrier" ::: "memory");
    asm volatile("s_waitcnt lgkmcnt(0)" ::: "memory");
    __builtin_amdgcn_s_setprio(1);
#pragma unroll
    for (int m = 0; m < 4; ++m)
#pragma unroll
      for (int n = 2; n < 4; ++n)
#pragma unroll
        for (int kk = 0; kk < 2; ++kk)
          acc[m][n] = __builtin_amdgcn_mfma_f32_16x16x32_bf16(af[m][kk], bfr[n][kk], acc[m][n], 0, 0, 0);
    __builtin_amdgcn_s_setprio(0);
    asm volatile("s_barrier" ::: "memory");
#pragma unroll
    for (int m = 0; m < 4; ++m)
#pragma unroll
      for (int kk = 0; kk < 2; ++kk) {
        const int row = wm + (m + 4) * 16 + l15;
        af[m][kk] = *(const bf16x8*)(Ab + row * 64 + ((kk * 32 + lg8) ^ ((row & 7) << 3)));
      }
    if (t + 2 < NT) { stB(cur, ktn2, 0); stB(cur, ktn2, 1); }
    asm volatile("s_barrier" ::: "memory");
    asm volatile("s_waitcnt lgkmcnt(0)" ::: "memory");
    __builtin_amdgcn_s_setprio(1);
#pragma unroll
    for (int m = 0; m < 4; ++m)
#pragma unroll
      for (int n = 0; n < 2; ++n)
#pragma unroll
        for (int kk = 0; kk < 2; ++kk)
          acc[m + 4][n] = __builtin_amdgcn_mfma_f32_16x16x32_bf16(af[m][kk], bfr[n][kk], acc[m + 4][n], 0, 0, 0);
    __builtin_amdgcn_s_setprio(0);
    asm volatile("s_barrier" ::: "memory");
    if (t + 2 < NT) { stB(cur, ktn2, 2); stB(cur, ktn2, 3); }
    asm volatile("s_waitcnt vmcnt(4)" ::: "memory");
    asm volatile("s_barrier" ::: "memory");
    __builtin_amdgcn_s_setprio(1);
#pragma unroll
    for (int m = 0; m < 4; ++m)
#pragma unroll
      for (int n = 2; n < 4; ++n)
#pragma unroll
        for (int kk = 0; kk < 2; ++kk)
          acc[m + 4][n] = __builtin_amdgcn_mfma_f32_16x16x32_bf16(af[m][kk], bfr[n][kk], acc[m + 4][n], 0, 0, 0);
    __builtin_amdgcn_s_setprio(0);
    asm volatile("s_barrier" ::: "memory");
  }

  const int cr = (lane >> 4) << 2;
#pragma unroll
  for (int m = 0; m < 8; ++m)
#pragma unroll
    for (int n = 0; n < 4; ++n)
#pragma unroll
      for (int j = 0; j < 4; ++j) {
        const size_t idx = (row0 + wm + m * 16 + cr + j) * (size_t)N + col0 + wn + n * 16 + l15;
        if constexpr (BF16OUT)
          ((unsigned short*)Cv)[idx] = f2bf(acc[m][n][j]);
        else
          ((float*)Cv)[idx] = acc[m][n][j];
      }
}

// ---------------- MFMA masked cross-attention ----------------
__global__ __launch_bounds__(256) void attn2_kernel(
    const unsigned short* __restrict__ qb,
    const unsigned short* __restrict__ kvb,
    const unsigned short* __restrict__ vt,
    const int* __restrict__ img_idx,
    unsigned short* __restrict__ attn_out) {
  __shared__ unsigned short Pl[4][64 * 72];
  const int tid = threadIdx.x;
  const int lane = tid & 63;
  const int w = tid >> 6;
  int bid = blockIdx.x;
  const int hg = bid & 3; bid >>= 2;
  const int tile = bid & 31; bid >>= 5;
  const int b = bid;
  const int t0 = tile * 64;
  const int h = hg * 4 + w;
  const int l15 = lane & 15;
  const int lg = lane >> 4;

  const int* ii = img_idx + b * T_ + t0;
  int myimg = ii[lane];
  int tmin = myimg, tmax = myimg;
#pragma unroll
  for (int off = 1; off < 64; off <<= 1) {
    tmin = min(tmin, __shfl_xor(tmin, off));
    tmax = max(tmax, __shfl_xor(tmax, off));
  }
  unsigned short* op = attn_out + (size_t)(b * T_ + t0) * INNER_ + h * DH_;
  if (tmin < 0) {
    for (int r = 0; r < 64; ++r)
      if (ii[r] < 0) op[(size_t)r * INNER_ + lane] = 0;
  }
  if (tmax < 0) return;

  bf16x8 qa[4][2];
  const unsigned short* qrow = qb + (size_t)(b * T_ + t0) * INNER_ + h * DH_;
#pragma unroll
  for (int m = 0; m < 4; ++m)
#pragma unroll
    for (int kk = 0; kk < 2; ++kk)
      qa[m][kk] = *(const bf16x8*)(qrow + (size_t)(l15 + m * 16) * INNER_ + kk * 32 + lg * 8);

  unsigned short* pw = Pl[w];
  for (int img = max(tmin, 0); img <= tmax; ++img) {
    const unsigned short* Kb = kvb + (size_t)(b * J_ + img * NLAT_) * (2 * INNER_) + h * DH_;
    f32x4 acc[4][4] = {};
#pragma unroll
    for (int kk = 0; kk < 2; ++kk) {
      bf16x8 bfr[4];
#pragma unroll
      for (int n = 0; n < 4; ++n)
        bfr[n] = *(const bf16x8*)(Kb + (size_t)(l15 + n * 16) * (2 * INNER_) + kk * 32 + lg * 8);
#pragma unroll
      for (int m = 0; m < 4; ++m)
#pragma unroll
        for (int n = 0; n < 4; ++n)
          acc[m][n] = __builtin_amdgcn_mfma_f32_16x16x32_bf16(qa[m][kk], bfr[n], acc[m][n], 0, 0, 0);
    }
#pragma unroll
    for (int m = 0; m < 4; ++m) {
#pragma unroll
      for (int j = 0; j < 4; ++j) {
        float mx = fmaxf(fmaxf(acc[m][0][j], acc[m][1][j]), fmaxf(acc[m][2][j], acc[m][3][j]));
#pragma unroll
        for (int off = 1; off < 16; off <<= 1) mx = fmaxf(mx, __shfl_xor(mx, off));
        float sum = 0.f;
#pragma unroll
        for (int n = 0; n < 4; ++n) {
          float e = __expf(acc[m][n][j] - mx);
          acc[m][n][j] = e;
          sum += e;
        }
#pragma unroll
        for (int off = 1; off < 16; off <<= 1) sum += __shfl_xor(sum, off);
        const float ri = 1.0f / sum;
        const int row = m * 16 + lg * 4 + j;
#pragma unroll
        for (int n = 0; n < 4; ++n)
          pw[row * 72 + n * 16 + l15] = f2bf(acc[m][n][j] * ri);
      }
    }
    const unsigned short* Vb = vt + (size_t)(b * INNER_ + h * DH_) * J_ + img * NLAT_;
    f32x4 oacc[4][4] = {};
#pragma unroll
    for (int kk = 0; kk < 2; ++kk) {
      bf16x8 pa[4], bfr[4];
#pragma unroll
      for (int m = 0; m < 4; ++m) {
        bf16x4 lo = *(const bf16x4*)(pw + (m * 16 + l15) * 72 + kk * 32 + lg * 8);
        bf16x4 hi = *(const bf16x4*)(pw + (m * 16 + l15) * 72 + kk * 32 + lg * 8 + 4);
        bf16x8 v;
#pragma unroll
        for (int e = 0; e < 4; ++e) { v[e] = lo[e]; v[e + 4] = hi[e]; }
        pa[m] = v;
      }
#pragma unroll
      for (int n = 0; n < 4; ++n)
        bfr[n] = *(const bf16x8*)(Vb + (size_t)(l15 + n * 16) * J_ + kk * 32 + lg * 8);
#pragma unroll
      for (int m = 0; m < 4; ++m)
#pragma unroll
        for (int n = 0; n < 4; ++n)
          oacc[m][n] = __builtin_amdgcn_mfma_f32_16x16x32_bf16(pa[m], bfr[n], oacc[m][n], 0, 0, 0);
    }
#pragma unroll
    for (int m = 0; m < 4; ++m)
#pragma unroll
      for (int j = 0; j < 4; ++j) {
        const int row = m * 16 + lg * 4 + j;
        if (ii[row] == img) {
#pragma unroll
          for (int n = 0; n < 4; ++n)
            op[(size_t)row * INNER_ + n * 16 + l15] = f2bf(oacc[m][n][j]);
        }
      }
  }
}

extern "C" void kernel_launch(void* const* d_in, const int* in_sizes, int n_in,
                              void* d_out, int out_size, void* d_ws, size_t ws_size,
                              hipStream_t stream) {
  const float* x = (const float*)d_in[0];
  const float* media = (const float*)d_in[1];
  const void* mloc = d_in[2];
  const float* gamma = (const float*)d_in[3];
  const float* beta = (const float*)d_in[4];
  const float* Wq = (const float*)d_in[5];
  const float* Wkv = (const float*)d_in[6];
  const float* Wout = (const float*)d_in[7];
  float* out = (float*)d_out;

  char* ws = (char*)d_ws;
  unsigned short* attn_out = (unsigned short*)(ws);
  unsigned short* wqt = (unsigned short*)(ws + 33554432);
  unsigned short* wkvt = (unsigned short*)(ws + 37748736);
  unsigned short* woutt = (unsigned short*)(ws + 41943040);
  unsigned short* medb = (unsigned short*)(ws + 46137344);
  unsigned short* qb = (unsigned short*)(ws + 50331648);
  unsigned short* kvb = (unsigned short*)(ws + 67108864);
  unsigned short* vt = (unsigned short*)(ws + 75497472);
  int* img_idx = (int*)(ws + 79691776);
  float* uvp = (float*)(ws + 79724544);
  float* vvp = (float*)(ws + 79790080);

  // prep: uv-partial(16) + scan(4) + Wq(512) + Wkv/Wout(1024) + media(1024) = 2580 blocks
  prep_kernel<<<2580, 256, 0, stream>>>(mloc, gamma, beta, Wq, Wkv, Wout, media,
                                        img_idx, wqt, wkvt, woutt, medb, uvp, vvp);
  // merged GEMM1(+LN) and GEMM2(+V-transpose): 128 gemm2 blocks + 256 gemm1 blocks
  g12_kernel<<<384, 512, 0, stream>>>(x, wqt, qb, uvp, vvp, medb, wkvt, kvb, vt);
  attn2_kernel<<<B_ * (T_ / 64) * 4, 256, 0, stream>>>(qb, kvb, vt, img_idx, attn_out);
  // GEMM3: out = attn_out @ woutt^T (M=8192,N=2048,K=1024) -> 256 blocks
  gemm256<false><<<(B_ * T_ / 256) * (D_ / 256), 512, 0, stream>>>(attn_out, woutt, out, B_ * T_, D_, INNER_);
}

// Round 17
// 149.906 us; speedup vs baseline: 1.0147x; 1.0147x over previous
//
#include <hip/hip_runtime.h>
#include <hip/hip_bf16.h>

#define B_ 4
#define T_ 2048
#define D_ 2048
#define DV_ 1024
#define TIMG_ 8
#define NLAT_ 64
#define H_ 16
#define DH_ 64
#define INNER_ 1024
#define J_ (TIMG_ * NLAT_)  // 512

using f32x4 = __attribute__((ext_vector_type(4))) float;
using bf16x8 = __attribute__((ext_vector_type(8))) short;
using bf16x4 = __attribute__((ext_vector_type(4))) short;

__device__ __forceinline__ unsigned short f2bf(float f) {
  union { float f; unsigned int u; } c{f};
  unsigned int r = c.u + 0x7FFFu + ((c.u >> 16) & 1u);  // RNE
  return (unsigned short)(r >> 16);
}

__device__ __forceinline__ void stage16(const unsigned short* g, unsigned short* l) {
  __builtin_amdgcn_global_load_lds(
      (const __attribute__((address_space(1))) unsigned int*)g,
      (__attribute__((address_space(3))) unsigned int*)l, 16, 0, 0);
}

// ========== prep v4: uv-partial(16) | scan(4) | Wq(512) | Wkv/Wout(1024) | media(1024) ==========
__global__ __launch_bounds__(256) void prep_kernel(
    const void* __restrict__ locs,
    const float* __restrict__ g, const float* __restrict__ bta,
    const float* __restrict__ Wq, const float* __restrict__ Wkv,
    const float* __restrict__ Wout, const float* __restrict__ media,
    int* __restrict__ img_idx,
    unsigned short* __restrict__ wqt, unsigned short* __restrict__ wkvt,
    unsigned short* __restrict__ woutt, unsigned short* __restrict__ medb,
    float* __restrict__ uvp, float* __restrict__ vvp) {
  __shared__ __align__(16) float smf[64 * 68];
  const int tid = threadIdx.x;
  int blk = blockIdx.x;

  if (blk < 16) {
    const int c4 = tid * 4;
    const float* wbase = Wq + (size_t)blk * 128 * INNER_ + c4;
    f32x4 u4 = {0.f, 0.f, 0.f, 0.f}, v4 = {0.f, 0.f, 0.f, 0.f};
    for (int k = 0; k < 128; ++k) {
      f32x4 w = *(const f32x4*)(wbase + (size_t)k * INNER_);
      const float gk = g[blk * 128 + k];
      const float bk = bta[blk * 128 + k];
      u4 += gk * w;
      v4 += bk * w;
    }
    *(f32x4*)(uvp + blk * INNER_ + c4) = u4 * 0.125f;
    *(f32x4*)(vvp + blk * INNER_ + c4) = v4 * 0.125f;
    return;
  }
  blk -= 16;
  if (blk < 4) {
    int* sm = (int*)smf;
    const int b = blk;
    const unsigned char* u8 = (const unsigned char*)locs;
    int cnt = 0;
    for (int i = tid; i < B_ * T_; i += 256) cnt += (u8[i] != 0) ? 1 : 0;
    sm[tid] = cnt;
    __syncthreads();
    for (int off = 128; off > 0; off >>= 1) {
      if (tid < off) sm[tid] += sm[tid + off];
      __syncthreads();
    }
    const bool u8mode = (sm[0] == B_ * TIMG_);
    __syncthreads();
    const int base = b * T_ + tid * 8;
    const int* i32 = (const int*)locs;
    int v[8];
    int ts = 0;
#pragma unroll
    for (int j = 0; j < 8; ++j) {
      v[j] = u8mode ? (u8[base + j] != 0 ? 1 : 0) : (i32[base + j] != 0 ? 1 : 0);
      ts += v[j];
    }
    sm[tid] = ts;
    __syncthreads();
    for (int off = 1; off < 256; off <<= 1) {
      int add = (tid >= off) ? sm[tid - off] : 0;
      __syncthreads();
      sm[tid] += add;
      __syncthreads();
    }
    int acc = sm[tid] - ts;
#pragma unroll
    for (int j = 0; j < 8; ++j) {
      acc += v[j];
      img_idx[base + j] = acc - 1;
    }
    return;
  }
  blk -= 4;
  if (blk < 512) {
    const int by = blk >> 4, bx = blk & 15;
    const int br = by * 64, bc = bx * 64;
    float (*tile)[68] = (float(*)[68])smf;
    const int r = tid >> 4;
    const int c4 = (tid & 15) * 4;
#pragma unroll
    for (int rr = 0; rr < 4; ++rr)
      *(float4*)&tile[r + rr * 16][c4] =
          *(const float4*)&Wq[(size_t)(br + r + rr * 16) * INNER_ + bc + c4];
    __syncthreads();
    const int oc = tid >> 2;
    const int rb = (tid & 3) * 16;
    bf16x8 o0, o1;
#pragma unroll
    for (int e = 0; e < 8; ++e) {
      o0[e] = (short)f2bf(tile[rb + e][oc] * g[br + rb + e] * 0.125f);
      o1[e] = (short)f2bf(tile[rb + 8 + e][oc] * g[br + rb + 8 + e] * 0.125f);
    }
    unsigned short* op = wqt + (size_t)(bc + oc) * D_ + br + rb;
    *(bf16x8*)op = o0;
    *(bf16x8*)(op + 8) = o1;
    return;
  }
  blk -= 512;
  if (blk < 1024) {
    const float* tin = (blk < 512) ? Wkv : Wout;
    unsigned short* tout = (blk < 512) ? wkvt : woutt;
    int idx = blk & 511;
    const int by = idx >> 5, bx = idx & 31;
    const int br = by * 64, bc = bx * 64;
    float (*tile)[68] = (float(*)[68])smf;
    const int r = tid >> 4;
    const int c4 = (tid & 15) * 4;
#pragma unroll
    for (int rr = 0; rr < 4; ++rr)
      *(float4*)&tile[r + rr * 16][c4] =
          *(const float4*)&tin[(size_t)(br + r + rr * 16) * (2 * INNER_) + bc + c4];
    __syncthreads();
    const int oc = tid >> 2;
    const int rb = (tid & 3) * 16;
    bf16x8 o0, o1;
#pragma unroll
    for (int e = 0; e < 8; ++e) {
      o0[e] = (short)f2bf(tile[rb + e][oc]);
      o1[e] = (short)f2bf(tile[rb + 8 + e][oc]);
    }
    unsigned short* op = tout + (size_t)(bc + oc) * DV_ + br + rb;
    *(bf16x8*)op = o0;
    *(bf16x8*)(op + 8) = o1;
    return;
  }
  blk -= 1024;
  const int i = blk * 512 + tid * 2;
  float4 a = ((const float4*)media)[i];
  float4 b2 = ((const float4*)media)[i + 1];
  ((ushort4*)medb)[i] = make_ushort4(f2bf(a.x), f2bf(a.y), f2bf(a.z), f2bf(a.w));
  ((ushort4*)medb)[i + 1] = make_ushort4(f2bf(b2.x), f2bf(b2.y), f2bf(b2.z), f2bf(b2.w));
}

// ========== gemm1_ln v5: 2-phase; acvt after P1 MFMA; XCD-grouped A-panel map ==========
__global__ __launch_bounds__(512, 2) void gemm1_ln(
    const float* __restrict__ Xg, const unsigned short* __restrict__ Bg,
    unsigned short* __restrict__ Cv,
    const float* __restrict__ uvp, const float* __restrict__ vvp) {
  const int N = INNER_, K = D_;
  __shared__ __align__(16) unsigned short lds[65536];
  const int tid = threadIdx.x;
  const int lane = tid & 63;
  const int wave = tid >> 6;
  const int l15 = lane & 15;
  const int lg8 = (lane >> 4) << 3;
  const int wr64 = (wave >> 2) << 6;
  const int wc16 = (wave & 3) << 4;

  const int bid = (int)blockIdx.x;
  const int xcd = bid & 7;
  const int i5 = bid >> 3;
  const long row0 = (long)(xcd * 8 + (i5 >> 2)) << 7;
  const long col0 = (long)(i5 & 3) << 8;

  const int ar = tid >> 2;
  const int aq = tid & 3;
  const float4* xrow = (const float4*)(Xg + (size_t)(row0 + ar) * K) + aq * 4;

  auto stB = [&](int t, int r) {
    const int i = r * 512 + tid;
    const int row = i >> 3;
    const int c = (i & 7) ^ (row & 7);
    stage16(Bg + (size_t)(col0 + row) * K + (t << 6) + c * 8,
            &lds[16384 + (t % 3) * 16384 + i * 8]);
  };

  float s_part = 0.f, sq_part = 0.f;
  float4 a0, a1, a2, a3;
  auto aload = [&](int t) {
    const float4* p = xrow + t * 16;
    a0 = p[0]; a1 = p[1]; a2 = p[2]; a3 = p[3];
  };
  auto acvt = [&](int t) {
    unsigned short* Ab = &lds[(t & 1) * 8192];
    float v0[8] = {a0.x, a0.y, a0.z, a0.w, a1.x, a1.y, a1.z, a1.w};
    float v1[8] = {a2.x, a2.y, a2.z, a2.w, a3.x, a3.y, a3.z, a3.w};
    bf16x8 w0, w1;
#pragma unroll
    for (int e = 0; e < 8; ++e) {
      s_part += v0[e] + v1[e];
      sq_part += v0[e] * v0[e] + v1[e] * v1[e];
      w0[e] = (short)f2bf(v0[e]);
      w1[e] = (short)f2bf(v1[e]);
    }
    *(bf16x8*)(Ab + ar * 64 + (((aq * 2) ^ (ar & 7)) << 3)) = w0;
    *(bf16x8*)(Ab + ar * 64 + (((aq * 2 + 1) ^ (ar & 7)) << 3)) = w1;
  };

  const int NT = K >> 6;  // 32
  aload(0); acvt(0);
  aload(1);
  stB(0, 0); stB(0, 1); stB(0, 2); stB(0, 3);
  stB(1, 0); stB(1, 1); stB(1, 2); stB(1, 3);
  asm volatile("s_waitcnt vmcnt(4)" ::: "memory");
  asm volatile("s_waitcnt lgkmcnt(0)" ::: "memory");
  asm volatile("s_barrier" ::: "memory");

  f32x4 acc[4][4] = {};
  for (int t = 0; t < NT; ++t) {
    const unsigned short* Ab = &lds[(t & 1) * 8192];
    const unsigned short* Bb = &lds[16384 + (t % 3) * 16384];
    bf16x8 af[4][2], bfr[4][2];
    // ---------- P1: ds A(all) + B n0-1; MFMA; then acvt/aload ----------
#pragma unroll
    for (int m = 0; m < 4; ++m)
#pragma unroll
      for (int kk = 0; kk < 2; ++kk) {
        const int row = wr64 + m * 16 + l15;
        af[m][kk] = *(const bf16x8*)(Ab + row * 64 + ((kk * 32 + lg8) ^ ((row & 7) << 3)));
      }
#pragma unroll
    for (int n = 0; n < 2; ++n)
#pragma unroll
      for (int kk = 0; kk < 2; ++kk) {
        const int brow = n * 64 + wc16 + l15;
        bfr[n][kk] = *(const bf16x8*)(Bb + brow * 64 + ((kk * 32 + lg8) ^ ((brow & 7) << 3)));
      }
    asm volatile("s_waitcnt lgkmcnt(0)" ::: "memory");
    __builtin_amdgcn_s_setprio(1);
#pragma unroll
    for (int m = 0; m < 4; ++m)
#pragma unroll
      for (int n = 0; n < 2; ++n)
#pragma unroll
        for (int kk = 0; kk < 2; ++kk)
          acc[m][n] = __builtin_amdgcn_mfma_f32_16x16x32_bf16(af[m][kk], bfr[n][kk], acc[m][n], 0, 0, 0);
    __builtin_amdgcn_s_setprio(0);
    if (t + 1 < NT) {
      acvt(t + 1);
      if (t + 2 < NT) aload(t + 2);
    }
    asm volatile("s_barrier" ::: "memory");
    // ---------- P2: ds B n2-3; stB(t+2); counted vmcnt; MFMA ----------
#pragma unroll
    for (int n = 2; n < 4; ++n)
#pragma unroll
      for (int kk = 0; kk < 2; ++kk) {
        const int brow = n * 64 + wc16 + l15;
        bfr[n][kk] = *(const bf16x8*)(Bb + brow * 64 + ((kk * 32 + lg8) ^ ((brow & 7) << 3)));
      }
    if (t + 2 < NT) {
      stB(t + 2, 0); stB(t + 2, 1); stB(t + 2, 2); stB(t + 2, 3);
      asm volatile("s_waitcnt vmcnt(8)" ::: "memory");
    } else {
      asm volatile("s_waitcnt vmcnt(0)" ::: "memory");
    }
    asm volatile("s_waitcnt lgkmcnt(0)" ::: "memory");
    __builtin_amdgcn_s_setprio(1);
#pragma unroll
    for (int m = 0; m < 4; ++m)
#pragma unroll
      for (int n = 2; n < 4; ++n)
#pragma unroll
        for (int kk = 0; kk < 2; ++kk)
          acc[m][n] = __builtin_amdgcn_mfma_f32_16x16x32_bf16(af[m][kk], bfr[n][kk], acc[m][n], 0, 0, 0);
    __builtin_amdgcn_s_setprio(0);
    asm volatile("s_barrier" ::: "memory");
  }

  // ---- stats reduce in A-region ----
  float* sred = (float*)lds;
  sred[tid] = s_part;
  sred[512 + tid] = sq_part;
  __syncthreads();
  if (tid < 128) {
    float s = sred[tid * 4] + sred[tid * 4 + 1] + sred[tid * 4 + 2] + sred[tid * 4 + 3];
    float sq = sred[512 + tid * 4] + sred[512 + tid * 4 + 1] + sred[512 + tid * 4 + 2] + sred[512 + tid * 4 + 3];
    float mu = s * (1.0f / D_);
    sred[1024 + tid] = mu;
    sred[1152 + tid] = rsqrtf(sq * (1.0f / D_) - mu * mu + 1e-5f);
  }
  __syncthreads();

  const int cr = (lane >> 4) << 2;
#pragma unroll
  for (int n = 0; n < 4; ++n) {
    const long col = col0 + n * 64 + wc16 + l15;
    float uu = 0.f, vv = 0.f;
#pragma unroll
    for (int i = 0; i < 16; ++i) {
      uu += uvp[i * INNER_ + col];
      vv += vvp[i * INNER_ + col];
    }
#pragma unroll
    for (int m = 0; m < 4; ++m)
#pragma unroll
      for (int j = 0; j < 4; ++j) {
        const int lr = wr64 + m * 16 + cr + j;
        const float mu = sred[1024 + lr];
        const float rstd = sred[1152 + lr];
        Cv[(row0 + lr) * (size_t)N + col] = f2bf(rstd * (acc[m][n][j] - mu * uu) + vv);
      }
  }
}

// ============ v2 128x256 2-phase GEMM; VSPLIT: V-col blocks write transposed to vt ============
template <bool BF16OUT, bool VSPLIT>
__global__ __launch_bounds__(512, 2) void gemm_bt2(const unsigned short* __restrict__ Ag,
                                                   const unsigned short* __restrict__ Bg,
                                                   void* __restrict__ Cv,
                                                   unsigned short* __restrict__ vtp,
                                                   int M, int N, int K) {
  __shared__ __align__(16) unsigned short lds[65536];
  const int tid = threadIdx.x;
  const int lane = tid & 63;
  const int wave = tid >> 6;
  const int l15 = lane & 15;
  const int lg8 = (lane >> 4) << 3;
  const int wr64 = (wave >> 2) << 6;
  const int wc16 = (wave & 3) << 4;

  const int nwg = gridDim.x;
  int wg = ((int)blockIdx.x & 7) * (nwg >> 3) + ((int)blockIdx.x >> 3);
  const int gridM = M >> 7;
  const long row0 = (long)(wg % gridM) << 7;
  const long col0 = (long)(wg / gridM) << 8;

  auto stA = [&](int t, int r) {
    const int i = r * 512 + tid;
    const int row = i >> 3;
    const int c = (i & 7) ^ (row & 7);
    stage16(Ag + (size_t)(row0 + row) * K + (t << 6) + c * 8,
            &lds[(t & 1) * 8192 + i * 8]);
  };
  auto stB = [&](int t, int r) {
    const int i = r * 512 + tid;
    const int row = i >> 3;
    const int c = (i & 7) ^ (row & 7);
    stage16(Bg + (size_t)(col0 + row) * K + (t << 6) + c * 8,
            &lds[16384 + (t % 3) * 16384 + i * 8]);
  };

  const int NT = K >> 6;
  stB(0, 0); stB(0, 1); stB(0, 2); stB(0, 3);
  stA(0, 0); stA(0, 1);
  stB(1, 0); stB(1, 1); stB(1, 2); stB(1, 3);
  asm volatile("s_waitcnt vmcnt(4)" ::: "memory");
  asm volatile("s_barrier" ::: "memory");

  f32x4 acc[4][4] = {};
  for (int t = 0; t < NT; ++t) {
    const unsigned short* Ab = &lds[(t & 1) * 8192];
    const unsigned short* Bb = &lds[16384 + (t % 3) * 16384];
    bf16x8 af[4][2], bfr[4][2];
#pragma unroll
    for (int m = 0; m < 4; ++m)
#pragma unroll
      for (int kk = 0; kk < 2; ++kk) {
        const int row = wr64 + m * 16 + l15;
        af[m][kk] = *(const bf16x8*)(Ab + row * 64 + ((kk * 32 + lg8) ^ ((row & 7) << 3)));
      }
#pragma unroll
    for (int n = 0; n < 2; ++n)
#pragma unroll
      for (int kk = 0; kk < 2; ++kk) {
        const int brow = n * 64 + wc16 + l15;
        bfr[n][kk] = *(const bf16x8*)(Bb + brow * 64 + ((kk * 32 + lg8) ^ ((brow & 7) << 3)));
      }
    if (t + 1 < NT) { stA(t + 1, 0); stA(t + 1, 1); }
    if (t + 2 < NT) { stB(t + 2, 0); stB(t + 2, 1); }
    asm volatile("s_barrier" ::: "memory");
    asm volatile("s_waitcnt lgkmcnt(0)" ::: "memory");
    __builtin_amdgcn_s_setprio(1);
#pragma unroll
    for (int m = 0; m < 4; ++m)
#pragma unroll
      for (int n = 0; n < 2; ++n)
#pragma unroll
        for (int kk = 0; kk < 2; ++kk)
          acc[m][n] = __builtin_amdgcn_mfma_f32_16x16x32_bf16(af[m][kk], bfr[n][kk], acc[m][n], 0, 0, 0);
    __builtin_amdgcn_s_setprio(0);
    asm volatile("s_barrier" ::: "memory");
#pragma unroll
    for (int n = 2; n < 4; ++n)
#pragma unroll
      for (int kk = 0; kk < 2; ++kk) {
        const int brow = n * 64 + wc16 + l15;
        bfr[n][kk] = *(const bf16x8*)(Bb + brow * 64 + ((kk * 32 + lg8) ^ ((brow & 7) << 3)));
      }
    if (t + 2 < NT) {
      stB(t + 2, 2); stB(t + 2, 3);
      asm volatile("s_waitcnt vmcnt(4)" ::: "memory");
    } else {
      asm volatile("s_waitcnt vmcnt(0)" ::: "memory");
    }
    asm volatile("s_barrier" ::: "memory");
    asm volatile("s_waitcnt lgkmcnt(0)" ::: "memory");
    __builtin_amdgcn_s_setprio(1);
#pragma unroll
    for (int m = 0; m < 4; ++m)
#pragma unroll
      for (int n = 2; n < 4; ++n)
#pragma unroll
        for (int kk = 0; kk < 2; ++kk)
          acc[m][n] = __builtin_amdgcn_mfma_f32_16x16x32_bf16(af[m][kk], bfr[n][kk], acc[m][n], 0, 0, 0);
    __builtin_amdgcn_s_setprio(0);
    asm volatile("s_barrier" ::: "memory");
  }

  const int cr = (lane >> 4) << 2;

  if constexpr (VSPLIT) {
    if (col0 >= INNER_) {
      __syncthreads();
      unsigned short* tp = lds;
#pragma unroll
      for (int m = 0; m < 4; ++m)
#pragma unroll
        for (int n = 0; n < 4; ++n)
#pragma unroll
          for (int j = 0; j < 4; ++j)
            tp[(n * 64 + wc16 + l15) * 136 + (wr64 + m * 16 + cr + j)] = f2bf(acc[m][n][j]);
      __syncthreads();
      const int dloc = tid >> 1;
      const int kh = (tid & 1) * 64;
      const int b = (int)(row0 >> 9);
      const int j0 = (int)(row0 & 511);
      unsigned short* dst = vtp + ((size_t)b * INNER_ + (col0 - INNER_) + dloc) * J_ + j0 + kh;
      const unsigned short* src = tp + dloc * 136 + kh;
#pragma unroll
      for (int e = 0; e < 8; ++e)
        *(bf16x8*)(dst + e * 8) = *(const bf16x8*)(src + e * 8);
      return;
    }
  }

#pragma unroll
  for (int m = 0; m < 4; ++m)
#pragma unroll
    for (int n = 0; n < 4; ++n)
#pragma unroll
      for (int j = 0; j < 4; ++j) {
        const size_t idx = (row0 + wr64 + m * 16 + cr + j) * (size_t)N + col0 + n * 64 + wc16 + l15;
        if constexpr (BF16OUT)
          ((unsigned short*)Cv)[idx] = f2bf(acc[m][n][j]);
        else
          ((float*)Cv)[idx] = acc[m][n][j];
      }
}

// ============ 256x256 deep-pipelined MFMA GEMM (4-phase, BK=64) ============
template <bool BF16OUT>
__global__ __launch_bounds__(512, 2) void gemm256(const unsigned short* __restrict__ Ag,
                                                  const unsigned short* __restrict__ Bg,
                                                  void* __restrict__ Cv,
                                                  int M, int N, int K) {
  __shared__ __align__(16) unsigned short lds[2][32768];
  const int tid = threadIdx.x;
  const int lane = tid & 63;
  const int wave = tid >> 6;
  const int l15 = lane & 15;
  const int lg8 = (lane >> 4) << 3;
  const int wm = (wave >> 2) << 7;
  const int wn = (wave & 3) << 6;

  const int nwg = gridDim.x;
  int wg = ((int)blockIdx.x & 7) * (nwg >> 3) + ((int)blockIdx.x >> 3);
  const int gridM = M >> 8;
  const long row0 = (long)(wg % gridM) << 8;
  const long col0 = (long)(wg / gridM) << 8;

  auto stA = [&](int buf, int kt, int r) {
    const int i = r * 512 + tid;
    const int row = i >> 3;
    const int c = (i & 7) ^ (row & 7);
    stage16(Ag + (size_t)(row0 + row) * K + kt + c * 8, &lds[buf][i * 8]);
  };
  auto stB = [&](int buf, int kt, int r) {
    const int i = r * 512 + tid;
    const int row = i >> 3;
    const int c = (i & 7) ^ (row & 7);
    stage16(Bg + (size_t)(col0 + row) * K + kt + c * 8, &lds[buf][16384 + i * 8]);
  };

  const int NT = K >> 6;
  stB(0, 0, 0); stB(0, 0, 1); stB(0, 0, 2); stB(0, 0, 3);
  stA(0, 0, 0); stA(0, 0, 1); stA(0, 0, 2); stA(0, 0, 3);
  stB(1, 64, 0); stB(1, 64, 1); stB(1, 64, 2); stB(1, 64, 3);
  asm volatile("s_waitcnt vmcnt(4)" ::: "memory");
  asm volatile("s_barrier" ::: "memory");

  f32x4 acc[8][4] = {};
  int cur = 0;
  for (int t = 0; t < NT; ++t, cur ^= 1) {
    const unsigned short* Ab = &lds[cur][0];
    const unsigned short* Bb = &lds[cur][16384];
    bf16x8 af[4][2], bfr[4][2];
    const int ktn = (t + 1) << 6;
    const int ktn2 = (t + 2) << 6;
#pragma unroll
    for (int m = 0; m < 4; ++m)
#pragma unroll
      for (int kk = 0; kk < 2; ++kk) {
        const int row = wm + m * 16 + l15;
        af[m][kk] = *(const bf16x8*)(Ab + row * 64 + ((kk * 32 + lg8) ^ ((row & 7) << 3)));
      }
#pragma unroll
    for (int n = 0; n < 2; ++n)
#pragma unroll
      for (int kk = 0; kk < 2; ++kk) {
        const int brow = wn + n * 16 + l15;
        bfr[n][kk] = *(const bf16x8*)(Bb + brow * 64 + ((kk * 32 + lg8) ^ ((brow & 7) << 3)));
      }
    if (t + 1 < NT) { stA(cur ^ 1, ktn, 0); stA(cur ^ 1, ktn, 1); }
    asm volatile("s_barrier" ::: "memory");
    asm volatile("s_waitcnt lgkmcnt(0)" ::: "memory");
    __builtin_amdgcn_s_setprio(1);
#pragma unroll
    for (int m = 0; m < 4; ++m)
#pragma unroll
      for (int n = 0; n < 2; ++n)
#pragma unroll
        for (int kk = 0; kk < 2; ++kk)
          acc[m][n] = __builtin_amdgcn_mfma_f32_16x16x32_bf16(af[m][kk], bfr[n][kk], acc[m][n], 0, 0, 0);
    __builtin_amdgcn_s_setprio(0);
    asm volatile("s_barrier" ::: "memory");
#pragma unroll
    for (int n = 2; n < 4; ++n)
#pragma unroll
      for (int kk = 0; kk < 2; ++kk) {
        const int brow = wn + n * 16 + l15;
        bfr[n][kk] = *(const bf16x8*)(Bb + brow * 64 + ((kk * 32 + lg8) ^ ((brow & 7) << 3)));
      }
    if (t + 1 < NT) { stA(cur ^ 1, ktn, 2); stA(cur ^ 1, ktn, 3); }
    asm volatile("s_barrier" ::: "memory");
    asm volatile("s_waitcnt lgkmcnt(0)" ::: "memory");
    __builtin_amdgcn_s_setprio(1);
#pragma unroll
    for (int m = 0; m < 4; ++m)
#pragma unroll
      for (int n = 2; n < 4; ++n)
#pragma unroll
        for (int kk = 0; kk < 2; ++kk)
          acc[m][n] = __builtin_amdgcn_mfma_f32_16x16x32_bf16(af[m][kk], bfr[n][kk], acc[m][n], 0, 0, 0);
    __builtin_amdgcn_s_setprio(0);
    asm volatile("s_barrier" ::: "memory");
#pragma unroll
    for (int m = 0; m < 4; ++m)
#pragma unroll
      for (int kk = 0; kk < 2; ++kk) {
        const int row = wm + (m + 4) * 16 + l15;
        af[m][kk] = *(const bf16x8*)(Ab + row * 64 + ((kk * 32 + lg8) ^ ((row & 7) << 3)));
      }
    if (t + 2 < NT) { stB(cur, ktn2, 0); stB(cur, ktn2, 1); }
    asm volatile("s_barrier" ::: "memory");
    asm volatile("s_waitcnt lgkmcnt(0)" ::: "memory");
    __builtin_amdgcn_s_setprio(1);
#pragma unroll
    for (int m = 0; m < 4; ++m)
#pragma unroll
      for (int n = 0; n < 2; ++n)
#pragma unroll
        for (int kk = 0; kk < 2; ++kk)
          acc[m + 4][n] = __builtin_amdgcn_mfma_f32_16x16x32_bf16(af[m][kk], bfr[n][kk], acc[m + 4][n], 0, 0, 0);
    __builtin_amdgcn_s_setprio(0);
    asm volatile("s_barrier" ::: "memory");
    if (t + 2 < NT) { stB(cur, ktn2, 2); stB(cur, ktn2, 3); }
    asm volatile("s_waitcnt vmcnt(4)" ::: "memory");
    asm volatile("s_barrier" ::: "memory");
    __builtin_amdgcn_s_setprio(1);
#pragma unroll
    for (int m = 0; m < 4; ++m)
#pragma unroll
      for (int n = 2; n < 4; ++n)
#pragma unroll
        for (int kk = 0; kk < 2; ++kk)
          acc[m + 4][n] = __builtin_amdgcn_mfma_f32_16x16x32_bf16(af[m][kk], bfr[n][kk], acc[m + 4][n], 0, 0, 0);
    __builtin_amdgcn_s_setprio(0);
    asm volatile("s_barrier" ::: "memory");
  }

  const int cr = (lane >> 4) << 2;
#pragma unroll
  for (int m = 0; m < 8; ++m)
#pragma unroll
    for (int n = 0; n < 4; ++n)
#pragma unroll
      for (int j = 0; j < 4; ++j) {
        const size_t idx = (row0 + wm + m * 16 + cr + j) * (size_t)N + col0 + wn + n * 16 + l15;
        if constexpr (BF16OUT)
          ((unsigned short*)Cv)[idx] = f2bf(acc[m][n][j]);
        else
          ((float*)Cv)[idx] = acc[m][n][j];
      }
}

// ---------------- MFMA masked cross-attention ----------------
__global__ __launch_bounds__(256) void attn2_kernel(
    const unsigned short* __restrict__ qb,
    const unsigned short* __restrict__ kvb,
    const unsigned short* __restrict__ vt,
    const int* __restrict__ img_idx,
    unsigned short* __restrict__ attn_out) {
  __shared__ unsigned short Pl[4][64 * 72];
  const int tid = threadIdx.x;
  const int lane = tid & 63;
  const int w = tid >> 6;
  int bid = blockIdx.x;
  const int hg = bid & 3; bid >>= 2;
  const int tile = bid & 31; bid >>= 5;
  const int b = bid;
  const int t0 = tile * 64;
  const int h = hg * 4 + w;
  const int l15 = lane & 15;
  const int lg = lane >> 4;

  const int* ii = img_idx + b * T_ + t0;
  int myimg = ii[lane];
  int tmin = myimg, tmax = myimg;
#pragma unroll
  for (int off = 1; off < 64; off <<= 1) {
    tmin = min(tmin, __shfl_xor(tmin, off));
    tmax = max(tmax, __shfl_xor(tmax, off));
  }
  unsigned short* op = attn_out + (size_t)(b * T_ + t0) * INNER_ + h * DH_;
  if (tmin < 0) {
    for (int r = 0; r < 64; ++r)
      if (ii[r] < 0) op[(size_t)r * INNER_ + lane] = 0;
  }
  if (tmax < 0) return;

  bf16x8 qa[4][2];
  const unsigned short* qrow = qb + (size_t)(b * T_ + t0) * INNER_ + h * DH_;
#pragma unroll
  for (int m = 0; m < 4; ++m)
#pragma unroll
    for (int kk = 0; kk < 2; ++kk)
      qa[m][kk] = *(const bf16x8*)(qrow + (size_t)(l15 + m * 16) * INNER_ + kk * 32 + lg * 8);

  unsigned short* pw = Pl[w];
  for (int img = max(tmin, 0); img <= tmax; ++img) {
    const unsigned short* Kb = kvb + (size_t)(b * J_ + img * NLAT_) * (2 * INNER_) + h * DH_;
    f32x4 acc[4][4] = {};
#pragma unroll
    for (int kk = 0; kk < 2; ++kk) {
      bf16x8 bfr[4];
#pragma unroll
      for (int n = 0; n < 4; ++n)
        bfr[n] = *(const bf16x8*)(Kb + (size_t)(l15 + n * 16) * (2 * INNER_) + kk * 32 + lg * 8);
#pragma unroll
      for (int m = 0; m < 4; ++m)
#pragma unroll
        for (int n = 0; n < 4; ++n)
          acc[m][n] = __builtin_amdgcn_mfma_f32_16x16x32_bf16(qa[m][kk], bfr[n], acc[m][n], 0, 0, 0);
    }
#pragma unroll
    for (int m = 0; m < 4; ++m) {
#pragma unroll
      for (int j = 0; j < 4; ++j) {
        float mx = fmaxf(fmaxf(acc[m][0][j], acc[m][1][j]), fmaxf(acc[m][2][j], acc[m][3][j]));
#pragma unroll
        for (int off = 1; off < 16; off <<= 1) mx = fmaxf(mx, __shfl_xor(mx, off));
        float sum = 0.f;
#pragma unroll
        for (int n = 0; n < 4; ++n) {
          float e = __expf(acc[m][n][j] - mx);
          acc[m][n][j] = e;
          sum += e;
        }
#pragma unroll
        for (int off = 1; off < 16; off <<= 1) sum += __shfl_xor(sum, off);
        const float ri = 1.0f / sum;
        const int row = m * 16 + lg * 4 + j;
#pragma unroll
        for (int n = 0; n < 4; ++n)
          pw[row * 72 + n * 16 + l15] = f2bf(acc[m][n][j] * ri);
      }
    }
    const unsigned short* Vb = vt + (size_t)(b * INNER_ + h * DH_) * J_ + img * NLAT_;
    f32x4 oacc[4][4] = {};
#pragma unroll
    for (int kk = 0; kk < 2; ++kk) {
      bf16x8 pa[4], bfr[4];
#pragma unroll
      for (int m = 0; m < 4; ++m) {
        bf16x4 lo = *(const bf16x4*)(pw + (m * 16 + l15) * 72 + kk * 32 + lg * 8);
        bf16x4 hi = *(const bf16x4*)(pw + (m * 16 + l15) * 72 + kk * 32 + lg * 8 + 4);
        bf16x8 v;
#pragma unroll
        for (int e = 0; e < 4; ++e) { v[e] = lo[e]; v[e + 4] = hi[e]; }
        pa[m] = v;
      }
#pragma unroll
      for (int n = 0; n < 4; ++n)
        bfr[n] = *(const bf16x8*)(Vb + (size_t)(l15 + n * 16) * J_ + kk * 32 + lg * 8);
#pragma unroll
      for (int m = 0; m < 4; ++m)
#pragma unroll
        for (int n = 0; n < 4; ++n)
          oacc[m][n] = __builtin_amdgcn_mfma_f32_16x16x32_bf16(pa[m], bfr[n], oacc[m][n], 0, 0, 0);
    }
#pragma unroll
    for (int m = 0; m < 4; ++m)
#pragma unroll
      for (int j = 0; j < 4; ++j) {
        const int row = m * 16 + lg * 4 + j;
        if (ii[row] == img) {
#pragma unroll
          for (int n = 0; n < 4; ++n)
            op[(size_t)row * INNER_ + n * 16 + l15] = f2bf(oacc[m][n][j]);
        }
      }
  }
}

extern "C" void kernel_launch(void* const* d_in, const int* in_sizes, int n_in,
                              void* d_out, int out_size, void* d_ws, size_t ws_size,
                              hipStream_t stream) {
  const float* x = (const float*)d_in[0];
  const float* media = (const float*)d_in[1];
  const void* mloc = d_in[2];
  const float* gamma = (const float*)d_in[3];
  const float* beta = (const float*)d_in[4];
  const float* Wq = (const float*)d_in[5];
  const float* Wkv = (const float*)d_in[6];
  const float* Wout = (const float*)d_in[7];
  float* out = (float*)d_out;

  char* ws = (char*)d_ws;
  unsigned short* attn_out = (unsigned short*)(ws);
  unsigned short* wqt = (unsigned short*)(ws + 33554432);
  unsigned short* wkvt = (unsigned short*)(ws + 37748736);
  unsigned short* woutt = (unsigned short*)(ws + 41943040);
  unsigned short* medb = (unsigned short*)(ws + 46137344);
  unsigned short* qb = (unsigned short*)(ws + 50331648);
  unsigned short* kvb = (unsigned short*)(ws + 67108864);
  unsigned short* vt = (unsigned short*)(ws + 75497472);
  int* img_idx = (int*)(ws + 79691776);
  float* uvp = (float*)(ws + 79724544);
  float* vvp = (float*)(ws + 79790080);

  prep_kernel<<<2580, 256, 0, stream>>>(mloc, gamma, beta, Wq, Wkv, Wout, media,
                                        img_idx, wqt, wkvt, woutt, medb, uvp, vvp);
  gemm1_ln<<<256, 512, 0, stream>>>(x, wqt, qb, uvp, vvp);
  gemm_bt2<true, true><<<(B_ * J_ / 128) * (2 * INNER_ / 256), 512, 0, stream>>>(
      medb, wkvt, kvb, vt, B_ * J_, 2 * INNER_, DV_);
  attn2_kernel<<<B_ * (T_ / 64) * 4, 256, 0, stream>>>(qb, kvb, vt, img_idx, attn_out);
  gemm256<false><<<(B_ * T_ / 256) * (D_ / 256), 512, 0, stream>>>(attn_out, woutt, out, B_ * T_, D_, INNER_);
}